// Round 1
// baseline (227.940 us; speedup 1.0000x reference)
//
#include <hip/hip_runtime.h>
#include <hip/hip_bf16.h>

// Problem constants (fixed by the reference)
#define NROWS 16384
#define SEQD  512
#define HIDD  1024
#define ENCD  256
#define NEXP  8
#define MAXTILES 136              // 16384/128 + 8 (one partial tile per expert)
#define MPAD_MAX (MAXTILES * 128) // 17408

using bf16 = __hip_bfloat16;
typedef __bf16 bf16x8 __attribute__((ext_vector_type(8)));
typedef float  f32x4  __attribute__((ext_vector_type(4)));

// ---------------- workspace layout (bytes) ----------------
// U (35,651,584 B) aliases [Xb|W1t|W2t|H] which are dead before GEMM3 runs.
enum : size_t {
  OFF_XB   = 0,                                  // 16384*512*2  = 16,777,216
  OFF_W1T  = OFF_XB  + (size_t)NROWS * SEQD * 2, // 1024*512*2   =  1,048,576
  OFF_W2T  = OFF_W1T + (size_t)HIDD * SEQD * 2,  // 256*1024*2   =    524,288
  OFF_H    = OFF_W2T + (size_t)ENCD * HIDD * 2,  // 16384*1024*2 = 33,554,432
  OFF_W3T  = OFF_H   + (size_t)NROWS * HIDD * 2, // 8*1024*256*2 =  4,194,304
  OFF_W4T  = OFF_W3T + (size_t)NEXP * HIDD * ENCD * 2, // 8*512*1024*2 = 8,388,608
  OFF_Z    = OFF_W4T + (size_t)NEXP * SEQD * HIDD * 2, // 16384*256*2 = 8,388,608
  OFF_PERM = OFF_Z   + (size_t)NROWS * ENCD * 2,
  OFF_META = OFF_PERM + (size_t)MPAD_MAX * 4,    // counts[8], fill[8], bases[9]
  OFF_U    = 0,
  WS_NEED  = OFF_META + 256
};

__device__ __forceinline__ void gload_lds16(const void* g, void* l) {
  __builtin_amdgcn_global_load_lds(
      (const __attribute__((address_space(1))) void*)g,
      (__attribute__((address_space(3))) void*)l, 16, 0, 0);
}

// ---------------- helper kernels ----------------

// f32 -> bf16 elementwise, 8 elems/thread
__global__ void cvtx_k(const float* __restrict__ src, bf16* __restrict__ dst) {
  int i = blockIdx.x * blockDim.x + threadIdx.x;
  float4 a = ((const float4*)src)[(size_t)i * 2];
  float4 b = ((const float4*)src)[(size_t)i * 2 + 1];
  __align__(16) bf16 v[8] = {
    __float2bfloat16(a.x), __float2bfloat16(a.y), __float2bfloat16(a.z), __float2bfloat16(a.w),
    __float2bfloat16(b.x), __float2bfloat16(b.y), __float2bfloat16(b.z), __float2bfloat16(b.w)};
  *(int4*)(dst + (size_t)i * 8) = *(const int4*)v;
}

// f32 [R,C] -> bf16 [C,R], batched via blockIdx.z
__global__ void tcvt_k(const float* __restrict__ src, bf16* __restrict__ dst, int R, int C) {
  __shared__ float t[32][33];
  const float* s = src + (size_t)blockIdx.z * R * C;
  bf16*       d  = dst + (size_t)blockIdx.z * R * C;
  int bx = blockIdx.x * 32, by = blockIdx.y * 32;
  int tx = threadIdx.x, ty = threadIdx.y;
  #pragma unroll
  for (int i = 0; i < 32; i += 8) t[ty + i][tx] = s[(size_t)(by + ty + i) * C + bx + tx];
  __syncthreads();
  #pragma unroll
  for (int i = 0; i < 32; i += 8)
    d[(size_t)(bx + ty + i) * R + by + tx] = __float2bfloat16(t[tx][ty + i]);
}

// meta layout: [0..7]=counts, [8..15]=fill, [16..24]=bases (bases[8]=padded total)
__global__ void count_k(const int* __restrict__ ids, int* __restrict__ meta) {
  __shared__ int c[NEXP];
  if (threadIdx.x < NEXP) c[threadIdx.x] = 0;
  __syncthreads();
  int base = (blockIdx.x * 256 + threadIdx.x) * 4;
  #pragma unroll
  for (int j = 0; j < 4; ++j) atomicAdd(&c[ids[base + j]], 1);
  __syncthreads();
  if (threadIdx.x < NEXP) atomicAdd(&meta[threadIdx.x], c[threadIdx.x]);
}

__global__ void bases_k(int* __restrict__ meta) {
  if (threadIdx.x == 0) {
    int tot = 0;
    for (int e = 0; e < NEXP; ++e) { meta[16 + e] = tot; tot += (meta[e] + 127) & ~127; }
    meta[24] = tot;
  }
}

__global__ void scatter_k(const int* __restrict__ ids, int* __restrict__ meta,
                          int* __restrict__ perm) {
  int base = (blockIdx.x * 256 + threadIdx.x) * 4;
  #pragma unroll
  for (int j = 0; j < 4; ++j) {
    int n = base + j;
    int e = ids[n];
    int pos = meta[16 + e] + atomicAdd(&meta[8 + e], 1);
    perm[pos] = n;
  }
}

// ---------------- 128x128 bf16 MFMA GEMM (m97 structure + T2 swizzle) ----------------
// C[m][n] = act( A[m,:] . Bt[n,:] + bias[n] )
// A: [M,K] bf16 row-major (optionally gathered rows via perm)
// Bt: [Ncols,K] bf16 row-major (per-expert stride Ncols*K in EXPERT mode)
template <bool GATHER_A, bool EXPERT, bool RELU, bool SCATTER_F32>
__global__ __launch_bounds__(256) void gemm128(
    const bf16* __restrict__ A, const bf16* __restrict__ Bt,
    const float* __restrict__ bias, void* __restrict__ Out,
    int Ncols, int K, const int* __restrict__ perm, const int* __restrict__ bases) {
  __shared__ char As[16384];  // [128 rows][64 bf16], XOR-swizzled: byte ^= (row&7)<<4
  __shared__ char Bs[16384];

  const int tid  = threadIdx.x;
  const int wid  = tid >> 6;
  const int lane = tid & 63;
  const int lm = lane & 15, l4 = lane >> 4;
  const int wm = wid >> 1, wn = wid & 1;

  const int tileM = blockIdx.x, tileN = blockIdx.y;
  int expert = 0;
  if (EXPERT) {
    const int total = bases[8];
    if (tileM * 128 >= total) return;  // uniform early-exit, before any barrier
    const int r0 = tileM * 128;
    #pragma unroll
    for (int e = 1; e < NEXP; ++e) expert += (r0 >= bases[e]) ? 1 : 0;
    Bt   += (size_t)expert * Ncols * K;
    bias += expert * Ncols;
  }
  const int row0 = tileM * 128, col0 = tileN * 128;

  // staging source pointers: 4 x (1KB per wave) per tile; LDS dest linear,
  // source pre-swizzled so swizzled reads see A[row][col].
  const bf16* gA[4];
  const bf16* gB[4];
  #pragma unroll
  for (int i = 0; i < 4; ++i) {
    int flat = (i * 4 + wid) * 1024 + lane * 16;       // byte position in LDS tile
    int r    = flat >> 7;                              // tile row 0..127
    int cb   = (flat & 127) ^ ((r & 7) << 4);          // pre-swizzled source byte col
    int arow;
    if (GATHER_A) {
      int p = perm[row0 + r];
      arow = (p < 0) ? 0 : p;                          // clamp padding rows
    } else {
      arow = row0 + r;
    }
    gA[i] = A  + (size_t)arow * K + (cb >> 1);
    gB[i] = Bt + (size_t)(col0 + r) * K + (cb >> 1);
  }

  f32x4 acc[4][4];
  #pragma unroll
  for (int i = 0; i < 4; ++i)
    #pragma unroll
    for (int j = 0; j < 4; ++j) { f32x4 z = {0.f, 0.f, 0.f, 0.f}; acc[i][j] = z; }

  // fragment LDS byte offsets (kk=0); kk=1 toggles bit6
  int aoff[4], boff[4];
  const int swz = (lm & 7) << 4;
  #pragma unroll
  for (int i = 0; i < 4; ++i) {
    int ar = wm * 64 + i * 16 + lm;
    aoff[i] = ar * 128 + ((l4 * 16) ^ swz);
    int br = wn * 64 + i * 16 + lm;
    boff[i] = br * 128 + ((l4 * 16) ^ swz);
  }

  const int nk = K >> 6;
  for (int kt = 0; kt < nk; ++kt) {
    #pragma unroll
    for (int i = 0; i < 4; ++i) {
      gload_lds16(gA[i] + kt * 64, As + (i * 4 + wid) * 1024);
      gload_lds16(gB[i] + kt * 64, Bs + (i * 4 + wid) * 1024);
    }
    __syncthreads();
    #pragma unroll
    for (int kk = 0; kk < 2; ++kk) {
      bf16x8 af[4], bfr[4];
      #pragma unroll
      for (int i = 0; i < 4; ++i) af[i]  = *(const bf16x8*)(As + (aoff[i] ^ (kk * 64)));
      #pragma unroll
      for (int i = 0; i < 4; ++i) bfr[i] = *(const bf16x8*)(Bs + (boff[i] ^ (kk * 64)));
      #pragma unroll
      for (int mi = 0; mi < 4; ++mi)
        #pragma unroll
        for (int ni = 0; ni < 4; ++ni)
          acc[mi][ni] = __builtin_amdgcn_mfma_f32_16x16x32_bf16(af[mi], bfr[ni], acc[mi][ni], 0, 0, 0);
    }
    __syncthreads();
  }

  // epilogue: D mapping col = lane&15 (N side), row = l4*4 + reg (M side)
  float bv[4];
  #pragma unroll
  for (int ni = 0; ni < 4; ++ni) bv[ni] = bias[col0 + wn * 64 + ni * 16 + lm];
  #pragma unroll
  for (int mi = 0; mi < 4; ++mi) {
    #pragma unroll
    for (int r = 0; r < 4; ++r) {
      int rowp = row0 + wm * 64 + mi * 16 + l4 * 4 + r;
      int orow = rowp;
      bool valid = true;
      if (SCATTER_F32) {
        int p = perm[rowp];
        valid = (p >= 0);
        orow  = valid ? p : 0;
      }
      #pragma unroll
      for (int ni = 0; ni < 4; ++ni) {
        float v = acc[mi][ni][r] + bv[ni];
        if (RELU) v = v > 0.f ? v : 0.f;
        int n = col0 + wn * 64 + ni * 16 + lm;
        if (SCATTER_F32) {
          if (valid) ((float*)Out)[(size_t)orow * Ncols + n] = v;
        } else {
          ((bf16*)Out)[(size_t)rowp * Ncols + n] = __float2bfloat16(v);
        }
      }
    }
  }
}

// ---------------- launch ----------------
extern "C" void kernel_launch(void* const* d_in, const int* in_sizes, int n_in,
                              void* d_out, int out_size, void* d_ws, size_t ws_size,
                              hipStream_t stream) {
  const float* x  = (const float*)d_in[0];
  const int*   ids= (const int*)d_in[1];
  const float* W1 = (const float*)d_in[2];
  const float* b1 = (const float*)d_in[3];
  const float* W2 = (const float*)d_in[4];
  const float* b2 = (const float*)d_in[5];
  const float* W3 = (const float*)d_in[6];
  const float* b3 = (const float*)d_in[7];
  const float* W4 = (const float*)d_in[8];
  const float* b4 = (const float*)d_in[9];

  char* ws = (char*)d_ws;
  bf16* Xb  = (bf16*)(ws + OFF_XB);
  bf16* W1t = (bf16*)(ws + OFF_W1T);
  bf16* W2t = (bf16*)(ws + OFF_W2T);
  bf16* W3t = (bf16*)(ws + OFF_W3T);
  bf16* W4t = (bf16*)(ws + OFF_W4T);
  bf16* H   = (bf16*)(ws + OFF_H);
  bf16* Z   = (bf16*)(ws + OFF_Z);
  bf16* U   = (bf16*)(ws + OFF_U);   // aliases Xb/W1t/W2t/H (dead by GEMM3)
  int*  perm  = (int*)(ws + OFF_PERM);
  int*  meta  = (int*)(ws + OFF_META);
  int*  bases = meta + 16;

  // zero counts+fill; perm = -1 (padding marker)
  hipMemsetAsync(meta, 0, 64, stream);
  hipMemsetAsync(perm, 0xFF, (size_t)MPAD_MAX * 4, stream);

  // conversions
  cvtx_k<<<dim3((NROWS * SEQD) / (256 * 8)), dim3(256), 0, stream>>>(x, Xb);
  tcvt_k<<<dim3(HIDD / 32, SEQD / 32, 1),    dim3(32, 8), 0, stream>>>(W1, W1t, SEQD, HIDD);
  tcvt_k<<<dim3(ENCD / 32, HIDD / 32, 1),    dim3(32, 8), 0, stream>>>(W2, W2t, HIDD, ENCD);
  tcvt_k<<<dim3(HIDD / 32, ENCD / 32, NEXP), dim3(32, 8), 0, stream>>>(W3, W3t, ENCD, HIDD);
  tcvt_k<<<dim3(SEQD / 32, HIDD / 32, NEXP), dim3(32, 8), 0, stream>>>(W4, W4t, HIDD, SEQD);

  // expert bucketing
  count_k  <<<dim3(16), dim3(256), 0, stream>>>(ids, meta);
  bases_k  <<<dim3(1),  dim3(64),  0, stream>>>(meta);
  scatter_k<<<dim3(16), dim3(256), 0, stream>>>(ids, meta, perm);

  // GEMM chain
  // 1) H = relu(Xb @ W1 + b1)            [16384,1024], K=512
  gemm128<false, false, true, false><<<dim3(NROWS / 128, HIDD / 128), dim3(256), 0, stream>>>(
      Xb, W1t, b1, H, HIDD, SEQD, nullptr, nullptr);
  // 2) Z = relu(H @ W2 + b2)             [16384,256], K=1024
  gemm128<false, false, true, false><<<dim3(NROWS / 128, ENCD / 128), dim3(256), 0, stream>>>(
      H, W2t, b2, Z, ENCD, HIDD, nullptr, nullptr);
  // 3) U = relu(gather(Z) @ W3[e] + b3[e])  padded rows, K=256
  gemm128<true, true, true, false><<<dim3(MAXTILES, HIDD / 128), dim3(256), 0, stream>>>(
      Z, W3t, b3, U, HIDD, ENCD, perm, bases);
  // 4) y[perm] = U @ W4[e] + b4[e]       f32 scatter, K=1024
  gemm128<false, true, false, true><<<dim3(MAXTILES, SEQD / 128), dim3(256), 0, stream>>>(
      U, W4t, b4, d_out, SEQD, HIDD, perm, bases);

  (void)in_sizes; (void)n_in; (void)out_size; (void)ws_size;
}

// Round 3
// 139.976 us; speedup vs baseline: 1.6284x; 1.6284x over previous
//
#include <hip/hip_runtime.h>
#include <hip/hip_bf16.h>

// Problem constants (fixed by the reference)
#define NROWS 16384
#define SEQD  512
#define HIDD  1024
#define ENCD  256
#define NEXP  8
#define NBLK  64                  // bucketing blocks (256 rows each)
#define MAXTILES 136              // 16384/128 + 8 (one partial tile per expert)
#define MPAD_MAX (MAXTILES * 128) // 17408

using bf16 = __hip_bfloat16;
typedef __bf16 bf16x8 __attribute__((ext_vector_type(8)));
typedef float  f32x4  __attribute__((ext_vector_type(4)));

// ---------------- workspace layout (bytes) ----------------
// U (35,651,584 B) aliases [Xb|W1t|W2t|H] which are dead before GEMM3 runs.
// Round-1 layout passed end-to-end => ws_size >= WS_NEED. Kept identical.
enum : size_t {
  OFF_XB   = 0,                                  // 16384*512*2  = 16,777,216
  OFF_W1T  = OFF_XB  + (size_t)NROWS * SEQD * 2, // 1024*512*2   =  1,048,576
  OFF_W2T  = OFF_W1T + (size_t)HIDD * SEQD * 2,  // 256*1024*2   =    524,288
  OFF_H    = OFF_W2T + (size_t)ENCD * HIDD * 2,  // 16384*1024*2 = 33,554,432
  OFF_W3T  = OFF_H   + (size_t)NROWS * HIDD * 2, // 8*1024*256*2 =  4,194,304
  OFF_W4T  = OFF_W3T + (size_t)NEXP * HIDD * ENCD * 2, // 8*512*1024*2 = 8,388,608
  OFF_Z    = OFF_W4T + (size_t)NEXP * SEQD * HIDD * 2, // 16384*256*2 = 8,388,608
  OFF_PERM = OFF_Z   + (size_t)NROWS * ENCD * 2,
  OFF_META = OFF_PERM + (size_t)MPAD_MAX * 4,
  OFF_U    = 0,
  WS_NEED  = OFF_META + 8192
};
// meta int layout: [0..511]=gh (per-block hist, 64x8), [512..520]=bases[9],
//                  [528..1039]=blockbase (64x8)

__device__ __forceinline__ void gload_lds16(const void* g, void* l) {
  __builtin_amdgcn_global_load_lds(
      (const __attribute__((address_space(1))) void*)g,
      (__attribute__((address_space(3))) void*)l, 16, 0, 0);
}

// ---------------- helper kernels ----------------

// f32 -> bf16 elementwise, 8 elems/thread
__global__ void cvtx_k(const float* __restrict__ src, bf16* __restrict__ dst) {
  int i = blockIdx.x * blockDim.x + threadIdx.x;
  float4 a = ((const float4*)src)[(size_t)i * 2];
  float4 b = ((const float4*)src)[(size_t)i * 2 + 1];
  __align__(16) bf16 v[8] = {
    __float2bfloat16(a.x), __float2bfloat16(a.y), __float2bfloat16(a.z), __float2bfloat16(a.w),
    __float2bfloat16(b.x), __float2bfloat16(b.y), __float2bfloat16(b.z), __float2bfloat16(b.w)};
  *(int4*)(dst + (size_t)i * 8) = *(const int4*)v;
}

// f32 [R,C] -> bf16 [C,R], batched via blockIdx.z
__global__ void tcvt_k(const float* __restrict__ src, bf16* __restrict__ dst, int R, int C) {
  __shared__ float t[32][33];
  const float* s = src + (size_t)blockIdx.z * R * C;
  bf16*       d  = dst + (size_t)blockIdx.z * R * C;
  int bx = blockIdx.x * 32, by = blockIdx.y * 32;
  int tx = threadIdx.x, ty = threadIdx.y;
  #pragma unroll
  for (int i = 0; i < 32; i += 8) t[ty + i][tx] = s[(size_t)(by + ty + i) * C + bx + tx];
  __syncthreads();
  #pragma unroll
  for (int i = 0; i < 32; i += 8)
    d[(size_t)(bx + ty + i) * R + by + tx] = __float2bfloat16(t[tx][ty + i]);
}

// ---- deterministic bucketing: perm is a pure function of ids (no global atomics)

// per-block histogram -> gh[block*8+e]
__global__ void count_k(const int* __restrict__ ids, int* __restrict__ gh) {
  __shared__ int c[NEXP];
  const int tid = threadIdx.x;
  if (tid < NEXP) c[tid] = 0;
  __syncthreads();
  atomicAdd(&c[ids[blockIdx.x * 256 + tid]], 1);  // LDS atomic: sum is order-invariant
  __syncthreads();
  if (tid < NEXP) gh[blockIdx.x * NEXP + tid] = c[tid];
}

// bases[e] = padded prefix of totals; blockbase[b][e] = bases[e] + sum_{b'<b} gh[b'][e]
__global__ void bases_k(int* __restrict__ meta) {
  int* gh        = meta;
  int* bases     = meta + 512;
  int* blockbase = meta + 528;
  __shared__ int counts[NEXP];
  __shared__ int base_s[NEXP + 1];
  const int tid = threadIdx.x;
  if (tid < NEXP) {
    int s = 0;
    for (int b = 0; b < NBLK; ++b) s += gh[b * NEXP + tid];
    counts[tid] = s;
  }
  __syncthreads();
  if (tid == 0) {
    int t = 0;
    for (int e = 0; e < NEXP; ++e) { base_s[e] = t; t += (counts[e] + 127) & ~127; }
    base_s[NEXP] = t;
  }
  __syncthreads();
  if (tid < NEXP) {
    int run = base_s[tid];
    for (int b = 0; b < NBLK; ++b) { blockbase[b * NEXP + tid] = run; run += gh[b * NEXP + tid]; }
  }
  if (tid == 0)
    for (int e = 0; e <= NEXP; ++e) bases[e] = base_s[e];
}

// stable-rank scatter: slot(n) = bases[e] + #{m < n : ids[m]==e}. Deterministic.
__global__ void scatter_k(const int* __restrict__ ids, const int* __restrict__ blockbase,
                          int* __restrict__ perm) {
  __shared__ int wavehist[4][NEXP];
  const int tid = threadIdx.x, w = tid >> 6, lane = tid & 63;
  const int n = blockIdx.x * 256 + tid;
  const int e = ids[n];
  const unsigned long long lt = (1ull << lane) - 1ull;
  int myrank = 0;
  #pragma unroll
  for (int ee = 0; ee < NEXP; ++ee) {
    unsigned long long bb = __ballot(e == ee);
    if (ee == e) myrank = __popcll(bb & lt);
    if (lane == 0) wavehist[w][ee] = __popcll(bb);
  }
  __syncthreads();
  int pre = 0;
  for (int w2 = 0; w2 < w; ++w2) pre += wavehist[w2][e];
  perm[blockbase[blockIdx.x * NEXP + e] + pre + myrank] = n;
}

// ---------------- 128x128 bf16 MFMA GEMM (m97 structure + T2 swizzle) ----------------
// C[m][n] = act( A[m,:] . Bt[n,:] + bias[n] )
// A: [M,K] bf16 row-major (optionally gathered rows via perm)
// Bt: [Ncols,K] bf16 row-major (per-expert stride Ncols*K in EXPERT mode)
template <bool GATHER_A, bool EXPERT, bool RELU, bool SCATTER_F32>
__global__ __launch_bounds__(256) void gemm128(
    const bf16* __restrict__ A, const bf16* __restrict__ Bt,
    const float* __restrict__ bias, void* __restrict__ Out,
    int Ncols, int K, const int* __restrict__ perm, const int* __restrict__ bases) {
  __shared__ char As[16384];  // [128 rows][64 bf16], XOR-swizzled: byte ^= (row&7)<<4
  __shared__ char Bs[16384];

  const int tid  = threadIdx.x;
  const int wid  = tid >> 6;
  const int lane = tid & 63;
  const int lm = lane & 15, l4 = lane >> 4;
  const int wm = wid >> 1, wn = wid & 1;

  const int tileM = blockIdx.x, tileN = blockIdx.y;
  int expert = 0;
  if (EXPERT) {
    const int total = bases[8];
    if (tileM * 128 >= total) return;  // uniform early-exit, before any barrier
    const int r0 = tileM * 128;
    #pragma unroll
    for (int e = 1; e < NEXP; ++e) expert += (r0 >= bases[e]) ? 1 : 0;
    Bt   += (size_t)expert * Ncols * K;
    bias += expert * Ncols;
  }
  const int row0 = tileM * 128, col0 = tileN * 128;

  // staging source pointers: 4 x (1KB per wave) per tile; LDS dest linear,
  // source pre-swizzled so swizzled reads see A[row][col].
  const bf16* gA[4];
  const bf16* gB[4];
  #pragma unroll
  for (int i = 0; i < 4; ++i) {
    int flat = (i * 4 + wid) * 1024 + lane * 16;       // byte position in LDS tile
    int r    = flat >> 7;                              // tile row 0..127
    int cb   = (flat & 127) ^ ((r & 7) << 4);          // pre-swizzled source byte col
    int arow;
    if (GATHER_A) {
      int p = perm[row0 + r];
      arow = (p < 0) ? 0 : p;                          // clamp padding rows
    } else {
      arow = row0 + r;
    }
    gA[i] = A  + (size_t)arow * K + (cb >> 1);
    gB[i] = Bt + (size_t)(col0 + r) * K + (cb >> 1);
  }

  f32x4 acc[4][4];
  #pragma unroll
  for (int i = 0; i < 4; ++i)
    #pragma unroll
    for (int j = 0; j < 4; ++j) { f32x4 z = {0.f, 0.f, 0.f, 0.f}; acc[i][j] = z; }

  // fragment LDS byte offsets (kk=0); kk=1 toggles bit6
  int aoff[4], boff[4];
  const int swz = (lm & 7) << 4;
  #pragma unroll
  for (int i = 0; i < 4; ++i) {
    int ar = wm * 64 + i * 16 + lm;
    aoff[i] = ar * 128 + ((l4 * 16) ^ swz);
    int br = wn * 64 + i * 16 + lm;
    boff[i] = br * 128 + ((l4 * 16) ^ swz);
  }

  const int nk = K >> 6;
  for (int kt = 0; kt < nk; ++kt) {
    #pragma unroll
    for (int i = 0; i < 4; ++i) {
      gload_lds16(gA[i] + kt * 64, As + (i * 4 + wid) * 1024);
      gload_lds16(gB[i] + kt * 64, Bs + (i * 4 + wid) * 1024);
    }
    __syncthreads();
    #pragma unroll
    for (int kk = 0; kk < 2; ++kk) {
      bf16x8 af[4], bfr[4];
      #pragma unroll
      for (int i = 0; i < 4; ++i) af[i]  = *(const bf16x8*)(As + (aoff[i] ^ (kk * 64)));
      #pragma unroll
      for (int i = 0; i < 4; ++i) bfr[i] = *(const bf16x8*)(Bs + (boff[i] ^ (kk * 64)));
      #pragma unroll
      for (int mi = 0; mi < 4; ++mi)
        #pragma unroll
        for (int ni = 0; ni < 4; ++ni)
          acc[mi][ni] = __builtin_amdgcn_mfma_f32_16x16x32_bf16(af[mi], bfr[ni], acc[mi][ni], 0, 0, 0);
    }
    __syncthreads();
  }

  // epilogue: D mapping col = lane&15 (N side), row = l4*4 + reg (M side)
  float bv[4];
  #pragma unroll
  for (int ni = 0; ni < 4; ++ni) bv[ni] = bias[col0 + wn * 64 + ni * 16 + lm];
  #pragma unroll
  for (int mi = 0; mi < 4; ++mi) {
    #pragma unroll
    for (int r = 0; r < 4; ++r) {
      int rowp = row0 + wm * 64 + mi * 16 + l4 * 4 + r;
      int orow = rowp;
      bool valid = true;
      if (SCATTER_F32) {
        int p = perm[rowp];
        valid = (p >= 0);
        orow  = valid ? p : 0;
      }
      #pragma unroll
      for (int ni = 0; ni < 4; ++ni) {
        float v = acc[mi][ni][r] + bv[ni];
        if (RELU) v = v > 0.f ? v : 0.f;
        int n = col0 + wn * 64 + ni * 16 + lm;
        if (SCATTER_F32) {
          if (valid) ((float*)Out)[(size_t)orow * Ncols + n] = v;
        } else {
          ((bf16*)Out)[(size_t)rowp * Ncols + n] = __float2bfloat16(v);
        }
      }
    }
  }
}

// ---------------- launch ----------------
extern "C" void kernel_launch(void* const* d_in, const int* in_sizes, int n_in,
                              void* d_out, int out_size, void* d_ws, size_t ws_size,
                              hipStream_t stream) {
  const float* x  = (const float*)d_in[0];
  const int*   ids= (const int*)d_in[1];
  const float* W1 = (const float*)d_in[2];
  const float* b1 = (const float*)d_in[3];
  const float* W2 = (const float*)d_in[4];
  const float* b2 = (const float*)d_in[5];
  const float* W3 = (const float*)d_in[6];
  const float* b3 = (const float*)d_in[7];
  const float* W4 = (const float*)d_in[8];
  const float* b4 = (const float*)d_in[9];

  char* ws = (char*)d_ws;
  bf16* Xb  = (bf16*)(ws + OFF_XB);
  bf16* W1t = (bf16*)(ws + OFF_W1T);
  bf16* W2t = (bf16*)(ws + OFF_W2T);
  bf16* W3t = (bf16*)(ws + OFF_W3T);
  bf16* W4t = (bf16*)(ws + OFF_W4T);
  bf16* H   = (bf16*)(ws + OFF_H);
  bf16* Z   = (bf16*)(ws + OFF_Z);
  bf16* U   = (bf16*)(ws + OFF_U);   // aliases Xb/W1t/W2t/H (dead by GEMM3)
  int*  perm      = (int*)(ws + OFF_PERM);
  int*  meta      = (int*)(ws + OFF_META);
  int*  gh        = meta;
  int*  bases     = meta + 512;
  int*  blockbase = meta + 528;

  // perm = -1 (padding marker). meta fully rewritten each call (no memset needed).
  hipMemsetAsync(perm, 0xFF, (size_t)MPAD_MAX * 4, stream);

  // conversions
  cvtx_k<<<dim3((NROWS * SEQD) / (256 * 8)), dim3(256), 0, stream>>>(x, Xb);
  tcvt_k<<<dim3(HIDD / 32, SEQD / 32, 1),    dim3(32, 8), 0, stream>>>(W1, W1t, SEQD, HIDD);
  tcvt_k<<<dim3(ENCD / 32, HIDD / 32, 1),    dim3(32, 8), 0, stream>>>(W2, W2t, HIDD, ENCD);
  tcvt_k<<<dim3(HIDD / 32, ENCD / 32, NEXP), dim3(32, 8), 0, stream>>>(W3, W3t, ENCD, HIDD);
  tcvt_k<<<dim3(SEQD / 32, HIDD / 32, NEXP), dim3(32, 8), 0, stream>>>(W4, W4t, HIDD, SEQD);

  // deterministic expert bucketing (perm is a pure function of ids)
  count_k  <<<dim3(NBLK), dim3(256), 0, stream>>>(ids, gh);
  bases_k  <<<dim3(1),    dim3(64),  0, stream>>>(meta);
  scatter_k<<<dim3(NBLK), dim3(256), 0, stream>>>(ids, blockbase, perm);

  // GEMM chain
  // 1) H = relu(Xb @ W1 + b1)            [16384,1024], K=512
  gemm128<false, false, true, false><<<dim3(NROWS / 128, HIDD / 128), dim3(256), 0, stream>>>(
      Xb, W1t, b1, H, HIDD, SEQD, nullptr, nullptr);
  // 2) Z = relu(H @ W2 + b2)             [16384,256], K=1024
  gemm128<false, false, true, false><<<dim3(NROWS / 128, ENCD / 128), dim3(256), 0, stream>>>(
      H, W2t, b2, Z, ENCD, HIDD, nullptr, nullptr);
  // 3) U = relu(gather(Z) @ W3[e] + b3[e])  padded rows, K=256
  gemm128<true, true, true, false><<<dim3(MAXTILES, HIDD / 128), dim3(256), 0, stream>>>(
      Z, W3t, b3, U, HIDD, ENCD, perm, bases);
  // 4) y[perm] = U @ W4[e] + b4[e]       f32 scatter, K=1024
  gemm128<false, true, false, true><<<dim3(MAXTILES, SEQD / 128), dim3(256), 0, stream>>>(
      U, W4t, b4, d_out, SEQD, HIDD, perm, bases);

  (void)in_sizes; (void)n_in; (void)out_size; (void)ws_size;
}